// Round 4
// baseline (254.955 us; speedup 1.0000x reference)
//
#include <hip/hip_runtime.h>
#include <math.h>

// Problem constants (match reference)
#define BB   64
#define SS   512
#define HH   768
#define NU   100    // token-MLP hidden units
#define NUP  112    // padded to 7*16
#define NT   7      // N tiles of 16
#define KS   24     // K steps of 32 (768/32)
#define NS1  300    // sentence-MLP hidden units
#define MM   (BB*SS)
#define PCH  16     // pool S-chunks per row
#define PTOK (SS/PCH) // 32 tokens per pool chunk

typedef __attribute__((ext_vector_type(8))) short short8;
typedef __attribute__((ext_vector_type(4))) float f32x4;

__device__ __forceinline__ unsigned short f2bf(float x) {
    unsigned int u = __float_as_uint(x);
    u = (u + 0x7FFFu + ((u >> 16) & 1u)) >> 16;   // round-to-nearest-even
    return (unsigned short)u;
}

__device__ __forceinline__ float tanh_fast(float x) {
    // tanh(x) = 1 - 2/(exp(2x)+1); __expf -> v_exp_f32, ~2ulp, correct at +-inf
    float e = __expf(2.0f * x);
    return 1.0f - 2.0f / (e + 1.0f);
}

__device__ __forceinline__ float sigmoid_fast(float z) {
    return 1.0f / (1.0f + __expf(-z));
}

// ---------------------------------------------------------------------------
// Kernel 0: repack w1 -> bf16 B-fragment buffer [NT][KS][64 lanes][8],
// zero-padded units 100..111. Also pad b1/w2 to 112 floats, zero accs+ticket.
// B-frag layout for mfma_f32_16x16x32_bf16: lane l holds B[(l>>4)*8+j][l&15].
// grid = NT*KS = 168 blocks, 64 threads.
// ---------------------------------------------------------------------------
__global__ __launch_bounds__(64) void repack_kernel(
    const float* __restrict__ w1,   // [H, NU]
    const float* __restrict__ b1,   // [NU]
    const float* __restrict__ w2,   // [NU]
    unsigned short* __restrict__ Bp,
    float* __restrict__ b1p, float* __restrict__ w2p,
    float* __restrict__ accs)       // 8 floats: zeroed here (incl. ticket)
{
    const int n  = blockIdx.x / KS;
    const int ks = blockIdx.x - n * KS;
    const int l  = threadIdx.x;
    const int c  = l & 15, g = l >> 4;
    const int u  = n * 16 + c;

    unsigned int w[4];
#pragma unroll
    for (int jp = 0; jp < 4; jp++) {
        unsigned int lo, hi;
        {
            int k = ks * 32 + g * 8 + jp * 2;
            float x = (u < NU) ? w1[(size_t)k * NU + u] : 0.0f;
            lo = f2bf(x);
        }
        {
            int k = ks * 32 + g * 8 + jp * 2 + 1;
            float x = (u < NU) ? w1[(size_t)k * NU + u] : 0.0f;
            hi = f2bf(x);
        }
        w[jp] = lo | (hi << 16);
    }
    uint4* dst = (uint4*)(Bp + ((size_t)(n * KS + ks) * 64 + l) * 8);
    *dst = make_uint4(w[0], w[1], w[2], w[3]);

    if (blockIdx.x == 0) {
        for (int i = l; i < NUP; i += 64) {
            b1p[i] = (i < NU) ? b1[i] : 0.0f;
            w2p[i] = (i < NU) ? w2[i] : 0.0f;
        }
        if (l < 8) accs[l] = 0.0f;   // [0..3] losses, [4] int ticket, rest spare
    }
}

// ---------------------------------------------------------------------------
// Kernel 1: tok = sigmoid(tanh(hs @ w1 + b1) @ w2 + b2) via bf16 MFMA.
// grid = M/64 = 512 blocks, 256 threads (4 waves x 16 tokens each).
// A-frag: lane l holds hs[m0 + (l&15)][k0 + (l>>4)*8 + j] (f32 -> bf16).
// D-frag: lane l holds D[(l>>4)*4 + j][l&15]  (row=token, col=unit).
// One-K-step register prefetch of A against ~200-900cy load latency
// (only 2 waves/SIMD at this grid).
// ---------------------------------------------------------------------------
__global__ __launch_bounds__(256) void tok_mlp_mfma(
    const float* __restrict__ hs,             // [M, H]
    const unsigned short* __restrict__ Bp,    // repacked w1
    const float* __restrict__ b1p,            // [NUP]
    const float* __restrict__ w2p,            // [NUP]
    const float* __restrict__ b2,             // [1]
    float* __restrict__ tok)                  // [M]
{
    const int tid = threadIdx.x;
    const int wv = tid >> 6, l = tid & 63;
    const int c = l & 15, g = l >> 4;
    const int m0 = blockIdx.x * 64 + wv * 16;

    f32x4 acc[NT];
#pragma unroll
    for (int n = 0; n < NT; n++) acc[n] = (f32x4){0.f, 0.f, 0.f, 0.f};

    const float* arow = hs + (size_t)(m0 + c) * HH + g * 8;
    const unsigned short* bbase = Bp + (size_t)l * 8;

    float4 a0 = *(const float4*)(arow);
    float4 a1 = *(const float4*)(arow + 4);

    for (int ks = 0; ks < KS; ks++) {
        float4 n0 = a0, n1 = a1;
        if (ks + 1 < KS) {
            n0 = *(const float4*)(arow + (ks + 1) * 32);
            n1 = *(const float4*)(arow + (ks + 1) * 32 + 4);
        }
        short8 af;
        af[0] = (short)f2bf(a0.x); af[1] = (short)f2bf(a0.y);
        af[2] = (short)f2bf(a0.z); af[3] = (short)f2bf(a0.w);
        af[4] = (short)f2bf(a1.x); af[5] = (short)f2bf(a1.y);
        af[6] = (short)f2bf(a1.z); af[7] = (short)f2bf(a1.w);
#pragma unroll
        for (int n = 0; n < NT; n++) {
            short8 bf = *(const short8*)(bbase + (size_t)(n * KS + ks) * 64 * 8);
            acc[n] = __builtin_amdgcn_mfma_f32_16x16x32_bf16(af, bf, acc[n], 0, 0, 0);
        }
        a0 = n0; a1 = n1;
    }

    // epilogue: per lane, 4 tokens (rows g*4+j) x 7 units (cols n*16+c)
    float p[4];
#pragma unroll
    for (int j = 0; j < 4; j++) {
        float s = 0.0f;
#pragma unroll
        for (int n = 0; n < NT; n++) {
            int u = n * 16 + c;
            s += tanh_fast(acc[n][j] + b1p[u]) * w2p[u];
        }
        p[j] = s;
    }
    // sum across the 16 cols (lanes sharing g)
#pragma unroll
    for (int off = 1; off < 16; off <<= 1) {
#pragma unroll
        for (int j = 0; j < 4; j++) p[j] += __shfl_xor(p[j], off, 64);
    }
    if (c == 0) {
        float bias = b2[0];
#pragma unroll
        for (int j = 0; j < 4; j++) {
            float z = p[j] + bias;
            tok[m0 + g * 4 + j] = sigmoid_fast(z);
        }
    }
}

// ---------------------------------------------------------------------------
// Kernel 2: per-row segmented max, masking, row reductions.
// grid = B = 64 blocks, 256 threads.
// ---------------------------------------------------------------------------
__global__ __launch_bounds__(256) void row_kernel(
    const float* __restrict__ tok,      // [M]
    const int*   __restrict__ offset,   // [B,S,2]
    const int*   __restrict__ labels,   // [B,S]
    float* __restrict__ masked_out,     // d_out + 5, [B,S]
    float* __restrict__ rowsum,         // [B]
    float* __restrict__ rowmax,         // [B]
    float* __restrict__ rowmin,         // [B]  (min of ones_mask)
    float* __restrict__ sentlab,        // [B]
    float* __restrict__ accs)           // [0]=token_loss
{
    __shared__ float tokL[SS];
    __shared__ float maskedL[SS];
    __shared__ int   startL[SS];
    __shared__ int   labL[SS];
    __shared__ float wredA[4][5];

    const int b = blockIdx.x, tid = threadIdx.x;

    for (int s = tid; s < SS; s += 256) {
        tokL[s]   = tok[b * SS + s];
        startL[s] = (offset[(size_t)(b * SS + s) * 2] == 0) ? 1 : 0;
        labL[s]   = labels[b * SS + s];
    }
    __syncthreads();

    for (int s = tid; s < SS; s += 256) {
        float w;
        if (startL[s]) {
            float m = tokL[s];
            for (int j = s + 1; j < SS && !startL[j]; j++) m = fmaxf(m, tokL[j]);
            w = m;
        } else {
            w = tokL[s];
        }
        int lab = labL[s];
        float maskv = (((lab == 0) || (lab == 1)) && startL[s]) ? 1.0f : 0.0f;
        float mk = w * maskv;
        maskedL[s] = mk;
        masked_out[b * SS + s] = mk;
    }
    __syncthreads();

    float psum = 0.0f, pmax = -INFINITY, pmin = INFINITY, pml = 0.0f, ploss = 0.0f;
    for (int s = tid; s < SS; s += 256) {
        float mk = maskedL[s];
        psum += mk;
        pmax = fmaxf(pmax, mk);
        float ones = (mk == 0.0f) ? 1.0f : mk;
        pmin = fminf(pmin, ones);
        float lf = (float)labL[s];
        pml = fmaxf(pml, lf);
        float zl = (lf == 1.0f) ? lf : 0.0f;   // zero_labels
        float d = mk - zl;
        ploss += d * d;
    }
#pragma unroll
    for (int off = 32; off >= 1; off >>= 1) {
        psum  += __shfl_xor(psum, off, 64);
        pmax   = fmaxf(pmax, __shfl_xor(pmax, off, 64));
        pmin   = fminf(pmin, __shfl_xor(pmin, off, 64));
        pml    = fmaxf(pml,  __shfl_xor(pml, off, 64));
        ploss += __shfl_xor(ploss, off, 64);
    }
    const int wv = tid >> 6, ln = tid & 63;
    if (ln == 0) {
        wredA[wv][0] = psum; wredA[wv][1] = pmax; wredA[wv][2] = pmin;
        wredA[wv][3] = pml;  wredA[wv][4] = ploss;
    }
    __syncthreads();
    if (tid == 0) {
        float s = 0.0f, mx = -INFINITY, mn = INFINITY, ml = 0.0f, ls = 0.0f;
        for (int w = 0; w < 4; w++) {
            s += wredA[w][0];
            mx = fmaxf(mx, wredA[w][1]);
            mn = fminf(mn, wredA[w][2]);
            ml = fmaxf(ml, wredA[w][3]);
            ls += wredA[w][4];
        }
        rowsum[b] = s; rowmax[b] = mx; rowmin[b] = mn; sentlab[b] = ml;
        atomicAdd(&accs[0], ls);
    }
}

// ---------------------------------------------------------------------------
// Kernel 3a: partial pooled[b,h] = sum_{s in chunk} hs[b,s,h]*norm[b,s]
// grid = B*PCH = 1024 blocks (16 S-chunks of 32), 192 threads (float4 per h4).
// Skips rows with norm == 0 (~30%): block-uniform compacted list, so the
// skip is whole-3KB-row granular and costs no coalescing.
// ---------------------------------------------------------------------------
__global__ __launch_bounds__(192) void pool_partial_kernel(
    const float* __restrict__ hs,       // [B,S,H]
    const float* __restrict__ masked,   // [B,S] (from d_out)
    const float* __restrict__ rowsum,   // [B]
    float* __restrict__ pp)             // [B,PCH,H]
{
    __shared__ float normL[PTOK];
    __shared__ float normC[PTOK];
    __shared__ int   idxC[PTOK];
    __shared__ int   cntS;
    const int b = blockIdx.x >> 4, p = blockIdx.x & 15;
    const int tid = threadIdx.x;
    const float inv = 1.0f / rowsum[b];
    if (tid < PTOK) normL[tid] = masked[b * SS + p * PTOK + tid] * inv;
    __syncthreads();
    if (tid == 0) {
        int c = 0;
        for (int s = 0; s < PTOK; s++) {
            float v = normL[s];
            if (v != 0.0f) { idxC[c] = s; normC[c] = v; c++; }
        }
        cntS = c;
    }
    __syncthreads();
    const int cnt = cntS;

    float4 a = make_float4(0.f, 0.f, 0.f, 0.f);
    const float* hb = hs + (size_t)b * SS * HH + (size_t)p * PTOK * HH;
#pragma unroll 2
    for (int i = 0; i < cnt; i++) {
        float w = normC[i];
        float4 v = *(const float4*)(hb + (size_t)idxC[i] * HH + tid * 4);
        a.x += v.x * w; a.y += v.y * w; a.z += v.z * w; a.w += v.w * w;
    }
    *(float4*)(pp + (size_t)(b * PCH + p) * HH + tid * 4) = a;
}

// ---------------------------------------------------------------------------
// Kernel 3b: sentence MLP + per-batch loss terms + (last block) finalize.
// grid = B = 64 blocks, 256 threads.
// ---------------------------------------------------------------------------
__global__ __launch_bounds__(256) void sent_kernel(
    const float* __restrict__ pp,       // [B,PCH,H]
    const float* __restrict__ sw1,      // [H,NS1]
    const float* __restrict__ sb1,      // [NS1]
    const float* __restrict__ sw2,      // [NS1]
    const float* __restrict__ sb2,      // [1]
    const float* __restrict__ rowmax,
    const float* __restrict__ rowmin,
    const float* __restrict__ sentlab,
    float* __restrict__ sent_out,       // d_out + 5 + M, [B]
    float* __restrict__ accs,           // [1]=sent_loss, [2]=reg_a, [3]=reg_b, [4]=ticket
    float* __restrict__ out)            // d_out scalars [0..4]
{
    __shared__ float pooledL[HH];
    __shared__ float t1L[NS1];
    __shared__ float wredB[4];

    const int b = blockIdx.x, tid = threadIdx.x;
#pragma unroll
    for (int j = 0; j < 3; j++) {
        int h = tid + j * 256;
        float s = 0.0f;
#pragma unroll
        for (int p = 0; p < PCH; p++) s += pp[(size_t)(b * PCH + p) * HH + h];
        pooledL[h] = s;
    }
    __syncthreads();

    for (int u = tid; u < NS1; u += 256) {
        float y = sb1[u];
        for (int h = 0; h < HH; h++) y += pooledL[h] * sw1[(size_t)h * NS1 + u];
        t1L[u] = tanh_fast(y);
    }
    __syncthreads();

    float z = 0.0f;
    for (int u = tid; u < NS1; u += 256) z += t1L[u] * sw2[u];
#pragma unroll
    for (int off = 32; off >= 1; off >>= 1) z += __shfl_xor(z, off, 64);
    const int wv = tid >> 6, ln = tid & 63;
    if (ln == 0) wredB[wv] = z;
    __syncthreads();
    if (tid == 0) {
        float zz = wredB[0] + wredB[1] + wredB[2] + wredB[3] + sb2[0];
        float sentv = sigmoid_fast(zz);
        sent_out[b] = sentv;
        float sl = sentlab[b];
        float ds = sentv - sl;
        atomicAdd(&accs[1], ds * ds);
        float dm = rowmax[b] - sl;
        atomicAdd(&accs[3], dm * dm);
        atomicAdd(&accs[2], rowmin[b] * rowmin[b]);

        // last-block finalize (device-scope ticket; atomic reads = coherent)
        __threadfence();
        int* ticket = (int*)(accs + 4);
        int old = atomicAdd(ticket, 1);
        if (old == BB - 1) {
            float tokl  = atomicAdd(&accs[0], 0.0f);
            float sentl = atomicAdd(&accs[1], 0.0f);
            float rega  = atomicAdd(&accs[2], 0.0f);
            float regb  = atomicAdd(&accs[3], 0.0f);
            out[0] = sentl + tokl + 0.01f * (rega + regb);
            out[1] = sentl;
            out[2] = tokl;
            out[3] = rega;
            out[4] = regb;
        }
    }
}

// ---------------------------------------------------------------------------
extern "C" void kernel_launch(void* const* d_in, const int* in_sizes, int n_in,
                              void* d_out, int out_size, void* d_ws, size_t ws_size,
                              hipStream_t stream)
{
    const float* hs     = (const float*)d_in[0];
    const int*   offm   = (const int*)  d_in[1];
    const int*   labels = (const int*)  d_in[2];
    const float* w1     = (const float*)d_in[3];
    const float* b1     = (const float*)d_in[4];
    const float* w2     = (const float*)d_in[5];
    const float* b2     = (const float*)d_in[6];
    const float* sw1    = (const float*)d_in[7];
    const float* sb1    = (const float*)d_in[8];
    const float* sw2    = (const float*)d_in[9];
    const float* sb2    = (const float*)d_in[10];

    float* out     = (float*)d_out;
    float* maskedO = out + 5;          // [B,S]
    float* sentO   = out + 5 + MM;     // [B]

    float* ws      = (float*)d_ws;
    float* tok     = ws;                          // M floats
    float* pp      = ws + MM;                     // B*PCH*H floats
    float* rowsum  = pp + (size_t)BB * PCH * HH;  // B
    float* rowmax  = rowsum + BB;
    float* rowmin  = rowmax + BB;
    float* sentlab = rowmin + BB;
    float* accs    = sentlab + BB;                // 8 floats (losses + ticket)
    float* b1p     = accs + 8;                    // NUP
    float* w2p     = b1p + NUP;                   // NUP
    // 16B-aligned bf16 fragment buffer
    size_t ofs = (size_t)((w2p + NUP) - ws);
    ofs = (ofs + 3) & ~(size_t)3;                 // align to 16B (4 floats)
    unsigned short* Bp = (unsigned short*)(ws + ofs);  // NT*KS*64*8 ushorts = 172 KB

    repack_kernel<<<NT * KS, 64, 0, stream>>>(w1, b1, w2, Bp, b1p, w2p, accs);
    tok_mlp_mfma<<<MM / 64, 256, 0, stream>>>(hs, Bp, b1p, w2p, b2, tok);
    row_kernel<<<BB, 256, 0, stream>>>(tok, offm, labels, maskedO,
                                       rowsum, rowmax, rowmin, sentlab, accs);
    pool_partial_kernel<<<BB * PCH, 192, 0, stream>>>(hs, maskedO, rowsum, pp);
    sent_kernel<<<BB, 256, 0, stream>>>(pp, sw1, sb1, sw2, sb2,
                                        rowmax, rowmin, sentlab, sentO, accs, out);
}

// Round 6
// 214.677 us; speedup vs baseline: 1.1876x; 1.1876x over previous
//
#include <hip/hip_runtime.h>
#include <math.h>

// Problem constants (match reference)
#define BB   64
#define SS   512
#define HH   768
#define NU   100    // token-MLP hidden units
#define NUP  112    // padded to 7*16
#define NT   7      // N tiles of 16
#define KS   24     // K steps of 32 (768/32)
#define NS1  300    // sentence-MLP hidden units
#define MM   (BB*SS)
#define PCH  16     // pool S-chunks per row
#define PTOK (SS/PCH) // 32 tokens per pool chunk
#define UB   5      // sent: unit-blocks per batch row
#define UPW  15     // sent: units per wave (UB * 4 waves * UPW = 300)

typedef __attribute__((ext_vector_type(8))) short short8;
typedef __attribute__((ext_vector_type(4))) float f32x4;

__device__ __forceinline__ unsigned short f2bf(float x) {
    unsigned int u = __float_as_uint(x);
    u = (u + 0x7FFFu + ((u >> 16) & 1u)) >> 16;   // round-to-nearest-even
    return (unsigned short)u;
}

__device__ __forceinline__ float tanh_fast(float x) {
    // tanh(x) = 1 - 2/(exp(2x)+1); __expf -> v_exp_f32, ~2ulp, correct at +-inf
    float e = __expf(2.0f * x);
    return 1.0f - 2.0f / (e + 1.0f);
}

__device__ __forceinline__ float sigmoid_fast(float z) {
    return 1.0f / (1.0f + __expf(-z));
}

// ---------------------------------------------------------------------------
// Kernel 0: blocks [0, NT*KS): repack w1 -> bf16 B-fragment buffer
// [NT][KS][64 lanes][8], zero-padded units 100..111; block 0 also pads b1/w2
// and zeroes accs/zacc/btick. Blocks [NT*KS, NT*KS+NS1): transpose
// sw1 [H,NS1] -> sw1T [NS1,H] (coalesced writes; scattered reads L2-hit).
// grid = NT*KS + NS1 = 468 blocks, 64 threads.
// ---------------------------------------------------------------------------
__global__ __launch_bounds__(64) void repack_kernel(
    const float* __restrict__ w1,   // [H, NU]
    const float* __restrict__ b1,   // [NU]
    const float* __restrict__ w2,   // [NU]
    const float* __restrict__ sw1,  // [H, NS1]
    unsigned short* __restrict__ Bp,
    float* __restrict__ b1p, float* __restrict__ w2p,
    float* __restrict__ sw1T,       // [NS1, H]
    float* __restrict__ accs,       // 8 floats (losses + global ticket)
    float* __restrict__ zacc,       // [BB] sent z accumulators
    int*   __restrict__ btick)      // [BB] per-b tickets
{
    const int blk = blockIdx.x;
    const int l   = threadIdx.x;

    if (blk < NT * KS) {
        const int n  = blk / KS;
        const int ks = blk - n * KS;
        const int c  = l & 15, g = l >> 4;
        const int u  = n * 16 + c;

        unsigned int w[4];
#pragma unroll
        for (int jp = 0; jp < 4; jp++) {
            unsigned int lo, hi;
            {
                int k = ks * 32 + g * 8 + jp * 2;
                float x = (u < NU) ? w1[(size_t)k * NU + u] : 0.0f;
                lo = f2bf(x);
            }
            {
                int k = ks * 32 + g * 8 + jp * 2 + 1;
                float x = (u < NU) ? w1[(size_t)k * NU + u] : 0.0f;
                hi = f2bf(x);
            }
            w[jp] = lo | (hi << 16);
        }
        uint4* dst = (uint4*)(Bp + ((size_t)(n * KS + ks) * 64 + l) * 8);
        *dst = make_uint4(w[0], w[1], w[2], w[3]);

        if (blk == 0) {
            for (int i = l; i < NUP; i += 64) {
                b1p[i] = (i < NU) ? b1[i] : 0.0f;
                w2p[i] = (i < NU) ? w2[i] : 0.0f;
            }
            if (l < 8) accs[l] = 0.0f;   // [0..3] losses, [4] int ticket
            zacc[l]  = 0.0f;
            btick[l] = 0;
        }
    } else {
        const int u = blk - NT * KS;     // 0..NS1-1
#pragma unroll
        for (int k = 0; k < HH / 64; k++) {
            int h = k * 64 + l;
            sw1T[(size_t)u * HH + h] = sw1[(size_t)h * NS1 + u];
        }
    }
}

// ---------------------------------------------------------------------------
// Kernel 1: tok = sigmoid(tanh(hs @ w1 + b1) @ w2 + b2) via bf16 MFMA.
// grid = M/64 = 512 blocks, 256 threads (4 waves x 16 tokens each).
// A-frag: lane l holds hs[m0 + (l&15)][k0 + (l>>4)*8 + j] (f32 -> bf16).
// D-frag: lane l holds D[(l>>4)*4 + j][l&15]  (row=token, col=unit).
// ---------------------------------------------------------------------------
__global__ __launch_bounds__(256) void tok_mlp_mfma(
    const float* __restrict__ hs,             // [M, H]
    const unsigned short* __restrict__ Bp,    // repacked w1
    const float* __restrict__ b1p,            // [NUP]
    const float* __restrict__ w2p,            // [NUP]
    const float* __restrict__ b2,             // [1]
    float* __restrict__ tok)                  // [M]
{
    const int tid = threadIdx.x;
    const int wv = tid >> 6, l = tid & 63;
    const int c = l & 15, g = l >> 4;
    const int m0 = blockIdx.x * 64 + wv * 16;

    f32x4 acc[NT];
#pragma unroll
    for (int n = 0; n < NT; n++) acc[n] = (f32x4){0.f, 0.f, 0.f, 0.f};

    const float* arow = hs + (size_t)(m0 + c) * HH + g * 8;
    const unsigned short* bbase = Bp + (size_t)l * 8;

    float4 a0 = *(const float4*)(arow);
    float4 a1 = *(const float4*)(arow + 4);

    for (int ks = 0; ks < KS; ks++) {
        float4 n0 = a0, n1 = a1;
        if (ks + 1 < KS) {
            n0 = *(const float4*)(arow + (ks + 1) * 32);
            n1 = *(const float4*)(arow + (ks + 1) * 32 + 4);
        }
        short8 af;
        af[0] = (short)f2bf(a0.x); af[1] = (short)f2bf(a0.y);
        af[2] = (short)f2bf(a0.z); af[3] = (short)f2bf(a0.w);
        af[4] = (short)f2bf(a1.x); af[5] = (short)f2bf(a1.y);
        af[6] = (short)f2bf(a1.z); af[7] = (short)f2bf(a1.w);
#pragma unroll
        for (int n = 0; n < NT; n++) {
            short8 bf = *(const short8*)(bbase + (size_t)(n * KS + ks) * 64 * 8);
            acc[n] = __builtin_amdgcn_mfma_f32_16x16x32_bf16(af, bf, acc[n], 0, 0, 0);
        }
        a0 = n0; a1 = n1;
    }

    // epilogue: per lane, 4 tokens (rows g*4+j) x 7 units (cols n*16+c)
    float p[4];
#pragma unroll
    for (int j = 0; j < 4; j++) {
        float s = 0.0f;
#pragma unroll
        for (int n = 0; n < NT; n++) {
            int u = n * 16 + c;
            s += tanh_fast(acc[n][j] + b1p[u]) * w2p[u];
        }
        p[j] = s;
    }
    // sum across the 16 cols (lanes sharing g)
#pragma unroll
    for (int off = 1; off < 16; off <<= 1) {
#pragma unroll
        for (int j = 0; j < 4; j++) p[j] += __shfl_xor(p[j], off, 64);
    }
    if (c == 0) {
        float bias = b2[0];
#pragma unroll
        for (int j = 0; j < 4; j++) {
            float z = p[j] + bias;
            tok[m0 + g * 4 + j] = sigmoid_fast(z);
        }
    }
}

// ---------------------------------------------------------------------------
// Kernel 2: per-row segmented max, masking, row reductions.
// grid = B = 64 blocks, 256 threads.
// ---------------------------------------------------------------------------
__global__ __launch_bounds__(256) void row_kernel(
    const float* __restrict__ tok,      // [M]
    const int*   __restrict__ offset,   // [B,S,2]
    const int*   __restrict__ labels,   // [B,S]
    float* __restrict__ masked_out,     // d_out + 5, [B,S]
    float* __restrict__ rowsum,         // [B]
    float* __restrict__ rowmax,         // [B]
    float* __restrict__ rowmin,         // [B]  (min of ones_mask)
    float* __restrict__ sentlab,        // [B]
    float* __restrict__ accs)           // [0]=token_loss
{
    __shared__ float tokL[SS];
    __shared__ float maskedL[SS];
    __shared__ int   startL[SS];
    __shared__ int   labL[SS];
    __shared__ float wredA[4][5];

    const int b = blockIdx.x, tid = threadIdx.x;

    for (int s = tid; s < SS; s += 256) {
        tokL[s]   = tok[b * SS + s];
        startL[s] = (offset[(size_t)(b * SS + s) * 2] == 0) ? 1 : 0;
        labL[s]   = labels[b * SS + s];
    }
    __syncthreads();

    for (int s = tid; s < SS; s += 256) {
        float w;
        if (startL[s]) {
            float m = tokL[s];
            for (int j = s + 1; j < SS && !startL[j]; j++) m = fmaxf(m, tokL[j]);
            w = m;
        } else {
            w = tokL[s];
        }
        int lab = labL[s];
        float maskv = (((lab == 0) || (lab == 1)) && startL[s]) ? 1.0f : 0.0f;
        float mk = w * maskv;
        maskedL[s] = mk;
        masked_out[b * SS + s] = mk;
    }
    __syncthreads();

    float psum = 0.0f, pmax = -INFINITY, pmin = INFINITY, pml = 0.0f, ploss = 0.0f;
    for (int s = tid; s < SS; s += 256) {
        float mk = maskedL[s];
        psum += mk;
        pmax = fmaxf(pmax, mk);
        float ones = (mk == 0.0f) ? 1.0f : mk;
        pmin = fminf(pmin, ones);
        float lf = (float)labL[s];
        pml = fmaxf(pml, lf);
        float zl = (lf == 1.0f) ? lf : 0.0f;   // zero_labels
        float d = mk - zl;
        ploss += d * d;
    }
#pragma unroll
    for (int off = 32; off >= 1; off >>= 1) {
        psum  += __shfl_xor(psum, off, 64);
        pmax   = fmaxf(pmax, __shfl_xor(pmax, off, 64));
        pmin   = fminf(pmin, __shfl_xor(pmin, off, 64));
        pml    = fmaxf(pml,  __shfl_xor(pml, off, 64));
        ploss += __shfl_xor(ploss, off, 64);
    }
    const int wv = tid >> 6, ln = tid & 63;
    if (ln == 0) {
        wredA[wv][0] = psum; wredA[wv][1] = pmax; wredA[wv][2] = pmin;
        wredA[wv][3] = pml;  wredA[wv][4] = ploss;
    }
    __syncthreads();
    if (tid == 0) {
        float s = 0.0f, mx = -INFINITY, mn = INFINITY, ml = 0.0f, ls = 0.0f;
        for (int w = 0; w < 4; w++) {
            s += wredA[w][0];
            mx = fmaxf(mx, wredA[w][1]);
            mn = fminf(mn, wredA[w][2]);
            ml = fmaxf(ml, wredA[w][3]);
            ls += wredA[w][4];
        }
        rowsum[b] = s; rowmax[b] = mx; rowmin[b] = mn; sentlab[b] = ml;
        atomicAdd(&accs[0], ls);
    }
}

// ---------------------------------------------------------------------------
// Kernel 3a: partial pooled[b,h] = sum_{s in chunk} hs[b,s,h]*norm[b,s]
// grid = B*PCH = 1024 blocks (16 S-chunks of 32), 192 threads (float4 per h4).
// Skips rows with norm == 0 (~30%): block-uniform compacted list.
// ---------------------------------------------------------------------------
__global__ __launch_bounds__(192) void pool_partial_kernel(
    const float* __restrict__ hs,       // [B,S,H]
    const float* __restrict__ masked,   // [B,S] (from d_out)
    const float* __restrict__ rowsum,   // [B]
    float* __restrict__ pp)             // [B,PCH,H]
{
    __shared__ float normL[PTOK];
    __shared__ float normC[PTOK];
    __shared__ int   idxC[PTOK];
    __shared__ int   cntS;
    const int b = blockIdx.x >> 4, p = blockIdx.x & 15;
    const int tid = threadIdx.x;
    const float inv = 1.0f / rowsum[b];
    if (tid < PTOK) normL[tid] = masked[b * SS + p * PTOK + tid] * inv;
    __syncthreads();
    if (tid == 0) {
        int c = 0;
        for (int s = 0; s < PTOK; s++) {
            float v = normL[s];
            if (v != 0.0f) { idxC[c] = s; normC[c] = v; c++; }
        }
        cntS = c;
    }
    __syncthreads();
    const int cnt = cntS;

    float4 a = make_float4(0.f, 0.f, 0.f, 0.f);
    const float* hb = hs + (size_t)b * SS * HH + (size_t)p * PTOK * HH;
#pragma unroll 2
    for (int i = 0; i < cnt; i++) {
        float w = normC[i];
        float4 v = *(const float4*)(hb + (size_t)idxC[i] * HH + tid * 4);
        a.x += v.x * w; a.y += v.y * w; a.z += v.z * w; a.w += v.w * w;
    }
    *(float4*)(pp + (size_t)(b * PCH + p) * HH + tid * 4) = a;
}

// ---------------------------------------------------------------------------
// Kernel 3b: sentence MLP + per-batch loss terms + finalize.
// grid = B*UB = 320 blocks, 256 threads. Each block: one b, 60 units;
// each wave: 15 units via 64-lane coalesced dot on sw1T + butterfly reduce.
// Cross-block z via per-b atomic + ticket; global ticket finalizes out[0..4].
// ---------------------------------------------------------------------------
__global__ __launch_bounds__(256) void sent_kernel(
    const float* __restrict__ pp,       // [B,PCH,H]
    const float* __restrict__ sw1T,     // [NS1,H]
    const float* __restrict__ sb1,      // [NS1]
    const float* __restrict__ sw2,      // [NS1]
    const float* __restrict__ sb2,      // [1]
    const float* __restrict__ rowmax,
    const float* __restrict__ rowmin,
    const float* __restrict__ sentlab,
    float* __restrict__ sent_out,       // d_out + 5 + M, [B]
    float* __restrict__ accs,           // [0..3] losses, [4]=global ticket
    float* __restrict__ zacc,           // [B]
    int*   __restrict__ btick,          // [B]
    float* __restrict__ out)            // d_out scalars [0..4]
{
    __shared__ float pooledL[HH];
    __shared__ float wzL[4];

    const int b = blockIdx.x / UB, ub = blockIdx.x - b * UB;
    const int tid = threadIdx.x;

    // pooled[b][:]: sum of PCH partials, 192 threads x float4
    if (tid < 192) {
        float4 s = make_float4(0.f, 0.f, 0.f, 0.f);
        const float* base = pp + (size_t)b * PCH * HH + tid * 4;
#pragma unroll
        for (int p = 0; p < PCH; p++) {
            float4 v = *(const float4*)(base + (size_t)p * HH);
            s.x += v.x; s.y += v.y; s.z += v.z; s.w += v.w;
        }
        *(float4*)(&pooledL[tid * 4]) = s;
    }
    __syncthreads();

    const int wv = tid >> 6, l = tid & 63;
    float zp = 0.0f;
#pragma unroll
    for (int i = 0; i < UPW; i++) {
        const int u = ub * (4 * UPW) + wv * UPW + i;
        const float* r = sw1T + (size_t)u * HH;
        float s = 0.0f;
#pragma unroll
        for (int k = 0; k < 3; k++) {
            float4 v  = *(const float4*)(r + (k * 64 + l) * 4);
            float4 pv = *(const float4*)(&pooledL[(k * 64 + l) * 4]);
            s += v.x * pv.x + v.y * pv.y + v.z * pv.z + v.w * pv.w;
        }
#pragma unroll
        for (int off = 32; off >= 1; off >>= 1) s += __shfl_xor(s, off, 64);
        zp += tanh_fast(s + sb1[u]) * sw2[u];
    }
    if (l == 0) wzL[wv] = zp;
    __syncthreads();

    if (tid == 0) {
        float blockz = wzL[0] + wzL[1] + wzL[2] + wzL[3];
        atomicAdd(&zacc[b], blockz);
        __threadfence();
        int old = atomicAdd(&btick[b], 1);
        if (old == UB - 1) {            // last block for this b
            float z = atomicAdd(&zacc[b], 0.0f) + sb2[0];
            float sentv = sigmoid_fast(z);
            sent_out[b] = sentv;
            float sl = sentlab[b];
            float ds = sentv - sl;
            atomicAdd(&accs[1], ds * ds);
            float dm = rowmax[b] - sl;
            atomicAdd(&accs[3], dm * dm);
            atomicAdd(&accs[2], rowmin[b] * rowmin[b]);
            __threadfence();
            int* t2 = (int*)(accs + 4);
            int o2 = atomicAdd(t2, 1);
            if (o2 == BB - 1) {         // last b finalizer
                float tokl  = atomicAdd(&accs[0], 0.0f);
                float sentl = atomicAdd(&accs[1], 0.0f);
                float rega  = atomicAdd(&accs[2], 0.0f);
                float regb  = atomicAdd(&accs[3], 0.0f);
                out[0] = sentl + tokl + 0.01f * (rega + regb);
                out[1] = sentl;
                out[2] = tokl;
                out[3] = rega;
                out[4] = regb;
            }
        }
    }
}

// ---------------------------------------------------------------------------
extern "C" void kernel_launch(void* const* d_in, const int* in_sizes, int n_in,
                              void* d_out, int out_size, void* d_ws, size_t ws_size,
                              hipStream_t stream)
{
    const float* hs     = (const float*)d_in[0];
    const int*   offm   = (const int*)  d_in[1];
    const int*   labels = (const int*)  d_in[2];
    const float* w1     = (const float*)d_in[3];
    const float* b1     = (const float*)d_in[4];
    const float* w2     = (const float*)d_in[5];
    const float* b2     = (const float*)d_in[6];
    const float* sw1    = (const float*)d_in[7];
    const float* sb1    = (const float*)d_in[8];
    const float* sw2    = (const float*)d_in[9];
    const float* sb2    = (const float*)d_in[10];

    float* out     = (float*)d_out;
    float* maskedO = out + 5;          // [B,S]
    float* sentO   = out + 5 + MM;     // [B]

    float* ws      = (float*)d_ws;
    float* tok     = ws;                          // M floats
    float* pp      = ws + MM;                     // B*PCH*H floats
    float* rowsum  = pp + (size_t)BB * PCH * HH;  // B
    float* rowmax  = rowsum + BB;
    float* rowmin  = rowmax + BB;
    float* sentlab = rowmin + BB;
    float* accs    = sentlab + BB;                // 8 floats (losses + ticket)
    float* zacc    = accs + 8;                    // BB
    float* btickf  = zacc + BB;                   // BB (int)
    float* b1p     = btickf + BB;                 // NUP
    float* w2p     = b1p + NUP;                   // NUP
    float* sw1T    = w2p + NUP;                   // NS1*HH floats
    // 16B-aligned bf16 fragment buffer
    size_t ofs = (size_t)((sw1T + (size_t)NS1 * HH) - ws);
    ofs = (ofs + 3) & ~(size_t)3;                 // align to 16B (4 floats)
    unsigned short* Bp = (unsigned short*)(ws + ofs);  // NT*KS*64*8 ushorts

    repack_kernel<<<NT * KS + NS1, 64, 0, stream>>>(w1, b1, w2, sw1, Bp, b1p, w2p,
                                                    sw1T, accs, zacc, (int*)btickf);
    tok_mlp_mfma<<<MM / 64, 256, 0, stream>>>(hs, Bp, b1p, w2p, b2, tok);
    row_kernel<<<BB, 256, 0, stream>>>(tok, offm, labels, maskedO,
                                       rowsum, rowmax, rowmin, sentlab, accs);
    pool_partial_kernel<<<BB * PCH, 192, 0, stream>>>(hs, maskedO, rowsum, pp);
    sent_kernel<<<BB * UB, 256, 0, stream>>>(pp, sw1T, sb1, sw2, sb2,
                                             rowmax, rowmin, sentlab, sentO,
                                             accs, zacc, (int*)btickf, out);
}